// Round 11
// baseline (24.613 us; speedup 1.0000x reference)
//
#include <hip/hip_runtime.h>

// StablePolicy3phase (round 11): MFMA + j-split across waves.
//
// out[r,:] = s·(Wsum + 0.001 I) - sum_j copysign(t_j, v_j(r)) grouped by j%3
//   j = 3h+c over 768 (head,comp) pairs; v_j = s·W_h[c,:]; t_j = bn <= 4e-4.
// Sign-trick + MFMA phases validated R10 (absmax 2.0 << 28).
//
// Phase A: C'[j,row] = mfma_16x16x32_bf16(W_rows, s)     (j-tile x 16-row stripe)
// Phase B: pack copysign(t_j, v) as bf16 pairs: v_perm + v_bfi per dword.
// Phase C: out_c += mfma(sel(j%3==c), packed, acc).
//
// R11 changes vs R10 (16.8us): each of the block's 4 waves owns 192 j's
// (6 groups) and processes all 8 stripes of the block; partials combined
// via LDS. aW registers 96->24 (kills spill risk), no sched_barriers
// (cross-group pipelining), grid 512->1024 (3+ waves/SIMD), tt reads as
// one b128/group, selv compile-time.

typedef short bf16x8 __attribute__((ext_vector_type(8)));
typedef float f32x4  __attribute__((ext_vector_type(4)));

#define VMAX_T 1.03f   // VMAX - 0.02
#define VMIN_T 0.97f   // VMIN + 0.02
#define SCALE_C 0.15f

__device__ __forceinline__ float deadband(float x) {
    return fmaxf(x - VMAX_T, 0.f) - fmaxf(VMIN_T - x, 0.f);
}
__device__ __forceinline__ unsigned bf16_rne(float x) {
    unsigned u = __float_as_uint(x);
    return (u + 0x7FFFu + ((u >> 16) & 1u)) >> 16;   // RNE bf16 in low 16
}
__device__ __forceinline__ unsigned pkbf(float a, float b) {
    return bf16_rne(a) | (bf16_rne(b) << 16);
}
__device__ __forceinline__ bf16x8 mk8(unsigned a, unsigned b, unsigned c, unsigned d) {
    uint4 u; u.x = a; u.y = b; u.z = c; u.w = d;
    return __builtin_bit_cast(bf16x8, u);
}
__device__ __forceinline__ unsigned sgnpair(float hi, float lo) {
    // dword: low16 = hi16(lo), high16 = hi16(hi)
    return __builtin_amdgcn_perm(__float_as_uint(hi), __float_as_uint(lo), 0x07060302u);
}
__device__ __forceinline__ unsigned csign(unsigned sgns, unsigned tpk) {
    return (sgns & 0x80008000u) | (tpk & 0x7FFF7FFFu);   // packed-bf16 copysign
}

__global__ __launch_bounds__(256, 3) void policy_mfma2(
    const float* __restrict__ state,
    const float* __restrict__ bvec,
    const float* __restrict__ lam,
    float* __restrict__ out, int B)
{
    // pool phase 1: wtab uint2[768] (6KB) | ttab u16[768] (1.5KB) | ttab2 uint4[96] (1.5KB)
    // pool phase 2 (after main loop + barrier): part f32[4][8][64][4] (32KB)
    __shared__ char pool[32768];
    __shared__ float red[4][8];

    uint2*          wtab  = (uint2*)pool;
    unsigned short* ttab  = (unsigned short*)(pool + 6144);
    uint4*          ttab2 = (uint4*)(pool + 6144 + 2048);
    float*          part  = (float*)pool;

    const int tid  = threadIdx.x;
    const int lane = tid & 63;
    const int wid  = tid >> 6;          // wave 0..3 = j-chunk owner
    const int l16  = lane & 15;
    const int grp  = lane >> 4;
    const bool low16 = (lane < 16);

    // ================= table build (head h = tid) ==========================
    const int h = tid;
    const float b0 = fmaxf(bvec[h*3+0], 0.f);
    const float b1 = fmaxf(bvec[h*3+1], 0.f);
    const float b2 = fmaxf(bvec[h*3+2], 0.f);
    float l0 = lam[h*6+0]; l0 *= l0;
    float l1 = lam[h*6+1]; l1 *= l1;
    float l2 = lam[h*6+2]; l2 *= l2;
    float l3 = lam[h*6+3]; l3 *= l3;
    float l4 = lam[h*6+4]; l4 *= l4;
    float l5 = lam[h*6+5]; l5 *= l5;
    // E order: (0,0),(1,0),(1,1),(2,0),(2,1),(2,2)
    const float w00 = l0+l1+l3, w01 = -l1, w02 = -l3;
    const float w11 = l1+l2+l4, w12 = -l4, w22 = l3+l4+l5;

    {
        float v0 = b0+b1+b2, v1 = w00, v2 = w01, v3 = w02, v4 = w11, v5 = w12, v6 = w22;
        #pragma unroll
        for (int off = 32; off > 0; off >>= 1) {
            v0 += __shfl_down(v0, off, 64); v1 += __shfl_down(v1, off, 64);
            v2 += __shfl_down(v2, off, 64); v3 += __shfl_down(v3, off, 64);
            v4 += __shfl_down(v4, off, 64); v5 += __shfl_down(v5, off, 64);
            v6 += __shfl_down(v6, off, 64);
        }
        if (lane == 0) {
            red[wid][0]=v0; red[wid][1]=v1; red[wid][2]=v2; red[wid][3]=v3;
            red[wid][4]=v4; red[wid][5]=v5; red[wid][6]=v6;
        }
    }

    {   // W rows (bf16) into LDS — no dependence on the reduction
        uint2 r0v; r0v.x = pkbf(w00, w01); r0v.y = pkbf(w02, 0.f);
        uint2 r1v; r1v.x = pkbf(w01, w11); r1v.y = pkbf(w12, 0.f);
        uint2 r2v; r2v.x = pkbf(w02, w12); r2v.y = pkbf(w22, 0.f);
        wtab[3*h+0] = r0v; wtab[3*h+1] = r1v; wtab[3*h+2] = r2v;
    }
    __syncthreads();

    const float S   = red[0][0]+red[1][0]+red[2][0]+red[3][0];
    const float Ws0 = red[0][1]+red[1][1]+red[2][1]+red[3][1];
    const float Ws1 = red[0][2]+red[1][2]+red[2][2]+red[3][2];
    const float Ws2 = red[0][3]+red[1][3]+red[2][3]+red[3][3];
    const float Ws3 = red[0][4]+red[1][4]+red[2][4]+red[3][4];
    const float Ws4 = red[0][5]+red[1][5]+red[2][5]+red[3][5];
    const float Ws5 = red[0][6]+red[1][6]+red[2][6]+red[3][6];
    const float inv = SCALE_C / S;

    ttab[3*h+0] = (unsigned short)bf16_rne(b0*inv);
    ttab[3*h+1] = (unsigned short)bf16_rne(b1*inv);
    ttab[3*h+2] = (unsigned short)bf16_rne(b2*inv);
    __syncthreads();

    if (tid < 96) {   // assemble per-(group, quadrant) t-pack: one b128 each
        const int gi = tid >> 2, g2 = tid & 3;
        const unsigned* tt32 = (const unsigned*)ttab;
        uint4 v;
        v.x = tt32[16*gi + 2*g2];
        v.y = tt32[16*gi + 2*g2 + 1];
        v.z = tt32[16*gi + 8 + 2*g2];
        v.w = tt32[16*gi + 8 + 2*g2 + 1];
        ttab2[tid] = v;
    }

    // ================= frags ==============================================
    // A-frags for this wave's 12 j-tiles (j = (12*wid + jl)*16 + l16)
    unsigned aW0[12], aW1[12];
    #pragma unroll
    for (int jl = 0; jl < 12; ++jl) {
        uint2 d = wtab[(12*wid + jl)*16 + l16];
        aW0[jl] = low16 ? d.x : 0u;
        aW1[jl] = low16 ? d.y : 0u;
    }

    // selection frags (R10-verified): A[c][slot] = 1.0 iff (p + j_local)%3 == c
    unsigned selA[3][4];
    #pragma unroll
    for (int p = 0; p < 3; ++p) {
        #pragma unroll
        for (int d = 0; d < 4; ++d) {
            const int k0 = grp*4 + (d & 1)*2 + (d >> 1)*16;
            const unsigned e0 = (((p + k0    ) % 3) == l16) ? 0x3F80u : 0u;
            const unsigned e1 = (((p + k0 + 1) % 3) == l16) ? 0x3F80u : 0u;
            selA[p][d] = e0 | (e1 << 16);
        }
    }
    const bf16x8 sel0 = mk8(selA[0][0], selA[0][1], selA[0][2], selA[0][3]);
    const bf16x8 sel1 = mk8(selA[1][0], selA[1][1], selA[1][2], selA[1][3]);
    const bf16x8 sel2 = mk8(selA[2][0], selA[2][1], selA[2][2], selA[2][3]);

    // state: 8 stripes of the block, every wave loads all of them
    const int rowbase = blockIdx.x * 128;
    float sf[8][3];
    bf16x8 bfv[8];
    #pragma unroll
    for (int i = 0; i < 8; ++i) {
        const int r = rowbase + i*16 + l16;
        float x0 = 1.f, x1 = 1.f, x2 = 1.f;
        if (r < B) { x0 = state[r*3+0]; x1 = state[r*3+1]; x2 = state[r*3+2]; }
        sf[i][0] = deadband(x0); sf[i][1] = deadband(x1); sf[i][2] = deadband(x2);
        const unsigned p0 = pkbf(sf[i][0], sf[i][1]);
        const unsigned p1 = bf16_rne(sf[i][2]);
        bfv[i] = mk8(low16 ? p0 : 0u, low16 ? p1 : 0u, 0u, 0u);
    }
    __syncthreads();   // ttab2 ready

    // ================= main: 6 groups x 8 stripes, no barriers =============
    const f32x4 cz = {0.f, 0.f, 0.f, 0.f};
    f32x4 cout[8] = {cz, cz, cz, cz, cz, cz, cz, cz};

#define STRIPE(i)                                                              \
    {                                                                          \
        f32x4 c0 = __builtin_amdgcn_mfma_f32_16x16x32_bf16(af0, bfv[i], cz, 0, 0, 0); \
        f32x4 c1 = __builtin_amdgcn_mfma_f32_16x16x32_bf16(af1, bfv[i], cz, 0, 0, 0); \
        const unsigned d0 = csign(sgnpair(c0[1], c0[0]), tp.x);                \
        const unsigned d1 = csign(sgnpair(c0[3], c0[2]), tp.y);                \
        const unsigned d2 = csign(sgnpair(c1[1], c1[0]), tp.z);                \
        const unsigned d3 = csign(sgnpair(c1[3], c1[2]), tp.w);                \
        cout[i] = __builtin_amdgcn_mfma_f32_16x16x32_bf16(selv, mk8(d0, d1, d2, d3), cout[i], 0, 0, 0); \
    }

    #pragma unroll
    for (int gl = 0; gl < 6; ++gl) {
        const uint4 tp = ttab2[(6*wid + gl)*4 + grp];
        const bf16x8 af0 = mk8(aW0[2*gl],   aW1[2*gl],   0u, 0u);
        const bf16x8 af1 = mk8(aW0[2*gl+1], aW1[2*gl+1], 0u, 0u);
        const int p = (2*gl) % 3;                      // wave-independent
        const bf16x8 selv = (p == 0) ? sel0 : (p == 1) ? sel1 : sel2;
        STRIPE(0) STRIPE(1) STRIPE(2) STRIPE(3)
        STRIPE(4) STRIPE(5) STRIPE(6) STRIPE(7)
    }
#undef STRIPE

    // ================= combine partials through LDS ========================
    __syncthreads();   // all table reads done; pool becomes `part`
    #pragma unroll
    for (int i = 0; i < 8; ++i)
        *(f32x4*)&part[((wid*8 + i)*64 + lane)*4] = cout[i];
    __syncthreads();

    // wave `wid` owns stripes 2*wid and 2*wid+1
    const float d00 = Ws0 + 0.001f, d11 = Ws3 + 0.001f, d22 = Ws5 + 0.001f;
    #pragma unroll
    for (int i = 0; i < 8; ++i) {
        if ((i >> 1) == wid) {                        // static sf/cout indexing
            f32x4 acc = *(const f32x4*)&part[((0*8 + i)*64 + lane)*4];
            acc += *(const f32x4*)&part[((1*8 + i)*64 + lane)*4];
            acc += *(const f32x4*)&part[((2*8 + i)*64 + lane)*4];
            acc += *(const f32x4*)&part[((3*8 + i)*64 + lane)*4];
            const int r = rowbase + i*16 + l16;
            if (low16 && r < B) {
                const float s0 = sf[i][0], s1 = sf[i][1], s2 = sf[i][2];
                out[r*3+0] = fmaf(s0, d00, fmaf(s1, Ws1, s2*Ws2)) - acc[0];
                out[r*3+1] = fmaf(s0, Ws1, fmaf(s1, d11, s2*Ws4)) - acc[1];
                out[r*3+2] = fmaf(s0, Ws2, fmaf(s1, Ws4, s2*d22)) - acc[2];
            }
        }
    }
}

extern "C" void kernel_launch(void* const* d_in, const int* in_sizes, int n_in,
                              void* d_out, int out_size, void* d_ws, size_t ws_size,
                              hipStream_t stream) {
    const float* state = (const float*)d_in[0];
    const float* bvec  = (const float*)d_in[1];
    const float* lam   = (const float*)d_in[2];
    float* out = (float*)d_out;

    const int B = in_sizes[0] / 3;   // 131072

    const int grid = (B + 127) / 128;   // 128 rows per 256-thread block
    hipLaunchKernelGGL(policy_mfma2, dim3(grid), dim3(256), 0, stream,
                       state, bvec, lam, out, B);
}

// Round 12
// 18.812 us; speedup vs baseline: 1.3084x; 1.3084x over previous
//
#include <hip/hip_runtime.h>

// StablePolicy3phase (round 12): R10 MFMA base + pipelining/occupancy fixes.
//
// out[r,:] = s·(Wsum + 0.001 I) - sum_j copysign(t_j, v_j(r)) grouped by j%3
//   j = 3h+c over 768 pairs; v_j = s·W_h[c,:]; t_j = bn <= 4e-4 (sum_j t = 0.15).
// Phase A: C'[j,row] = mfma_16x16x32_bf16(W_rows, s); Phase B: v_perm+bfi pack
// copysign(t,v) to bf16 pairs; Phase C: out_c += mfma(sel(j%3==c), packed).
// All validated in R10 (absmax 2.0). R11's j-split/combine regressed both
// metrics (cause not isolated) -> reverted; this is R10 + exactly two fixes:
//  1. A-frags via in-loop LDS broadcast reads (kills the 96-VGPR aW table and
//     the per-group sched_barrier serialization).
//  2. 2 stripes/wave, grid 1024, launch_bounds(256,4) -> 4 waves/SIMD.
// MFMA floor 4.7us; LDS pipe ~10k cyc/CU co-bottleneck.

typedef short bf16x8 __attribute__((ext_vector_type(8)));
typedef float f32x4  __attribute__((ext_vector_type(4)));

#define VMAX_T 1.03f   // VMAX - 0.02
#define VMIN_T 0.97f   // VMIN + 0.02
#define SCALE_C 0.15f

__device__ __forceinline__ float deadband(float x) {
    return fmaxf(x - VMAX_T, 0.f) - fmaxf(VMIN_T - x, 0.f);
}
__device__ __forceinline__ unsigned bf16_rne(float x) {
    unsigned u = __float_as_uint(x);
    return (u + 0x7FFFu + ((u >> 16) & 1u)) >> 16;   // RNE bf16 in low 16
}
__device__ __forceinline__ unsigned pkbf(float a, float b) {
    return bf16_rne(a) | (bf16_rne(b) << 16);
}
__device__ __forceinline__ bf16x8 mk8(unsigned a, unsigned b, unsigned c, unsigned d) {
    uint4 u; u.x = a; u.y = b; u.z = c; u.w = d;
    return __builtin_bit_cast(bf16x8, u);
}
__device__ __forceinline__ unsigned sgnpair(float hi, float lo) {
    // dword: low16 = hi16(lo), high16 = hi16(hi)
    return __builtin_amdgcn_perm(__float_as_uint(hi), __float_as_uint(lo), 0x07060302u);
}
__device__ __forceinline__ unsigned csign(unsigned sgns, unsigned tpk) {
    return (sgns & 0x80008000u) | (tpk & 0x7FFF7FFFu);   // packed-bf16 copysign
}

__global__ __launch_bounds__(256, 4) void policy_mfma3(
    const float* __restrict__ state,
    const float* __restrict__ bvec,
    const float* __restrict__ lam,
    float* __restrict__ out, int B)
{
    __shared__ uint2 wtab[768];            // 6 KB   (per j: pk(Wr0,Wr1), pk(Wr2,0))
    __shared__ unsigned short ttab[768];   // 1.5 KB (bf16 t_j)
    __shared__ uint4 ttab2[96];            // 1.5 KB (per (group,grp): 4 t-dwords)
    __shared__ float red[4][8];

    const int tid  = threadIdx.x;
    const int lane = tid & 63;
    const int wid  = tid >> 6;
    const int l16  = lane & 15;
    const int grp  = lane >> 4;
    const bool low16 = (lane < 16);

    // ================= table build (head h = tid) — R10 verbatim ===========
    const int h = tid;
    const float b0 = fmaxf(bvec[h*3+0], 0.f);
    const float b1 = fmaxf(bvec[h*3+1], 0.f);
    const float b2 = fmaxf(bvec[h*3+2], 0.f);
    float l0 = lam[h*6+0]; l0 *= l0;
    float l1 = lam[h*6+1]; l1 *= l1;
    float l2 = lam[h*6+2]; l2 *= l2;
    float l3 = lam[h*6+3]; l3 *= l3;
    float l4 = lam[h*6+4]; l4 *= l4;
    float l5 = lam[h*6+5]; l5 *= l5;
    // E order: (0,0),(1,0),(1,1),(2,0),(2,1),(2,2)
    const float w00 = l0+l1+l3, w01 = -l1, w02 = -l3;
    const float w11 = l1+l2+l4, w12 = -l4, w22 = l3+l4+l5;

    {   // block reduction of {bsum, Wsum x6}
        float v0 = b0+b1+b2, v1 = w00, v2 = w01, v3 = w02, v4 = w11, v5 = w12, v6 = w22;
        #pragma unroll
        for (int off = 32; off > 0; off >>= 1) {
            v0 += __shfl_down(v0, off, 64); v1 += __shfl_down(v1, off, 64);
            v2 += __shfl_down(v2, off, 64); v3 += __shfl_down(v3, off, 64);
            v4 += __shfl_down(v4, off, 64); v5 += __shfl_down(v5, off, 64);
            v6 += __shfl_down(v6, off, 64);
        }
        if (lane == 0) {
            red[wid][0]=v0; red[wid][1]=v1; red[wid][2]=v2; red[wid][3]=v3;
            red[wid][4]=v4; red[wid][5]=v5; red[wid][6]=v6;
        }
    }
    {   // W rows (bf16) into LDS
        uint2 r0v; r0v.x = pkbf(w00, w01); r0v.y = pkbf(w02, 0.f);
        uint2 r1v; r1v.x = pkbf(w01, w11); r1v.y = pkbf(w12, 0.f);
        uint2 r2v; r2v.x = pkbf(w02, w12); r2v.y = pkbf(w22, 0.f);
        wtab[3*h+0] = r0v; wtab[3*h+1] = r1v; wtab[3*h+2] = r2v;
    }
    __syncthreads();

    const float S   = red[0][0]+red[1][0]+red[2][0]+red[3][0];
    const float Ws0 = red[0][1]+red[1][1]+red[2][1]+red[3][1];
    const float Ws1 = red[0][2]+red[1][2]+red[2][2]+red[3][2];
    const float Ws2 = red[0][3]+red[1][3]+red[2][3]+red[3][3];
    const float Ws3 = red[0][4]+red[1][4]+red[2][4]+red[3][4];
    const float Ws4 = red[0][5]+red[1][5]+red[2][5]+red[3][5];
    const float Ws5 = red[0][6]+red[1][6]+red[2][6]+red[3][6];
    const float inv = SCALE_C / S;

    ttab[3*h+0] = (unsigned short)bf16_rne(b0*inv);
    ttab[3*h+1] = (unsigned short)bf16_rne(b1*inv);
    ttab[3*h+2] = (unsigned short)bf16_rne(b2*inv);
    __syncthreads();

    if (tid < 96) {   // per-(group, quadrant) t-pack: matches R10's 4 reads
        const int gi = tid >> 2, g2 = tid & 3;
        const unsigned* tt32 = (const unsigned*)ttab;
        uint4 v;
        v.x = tt32[16*gi + 2*g2];
        v.y = tt32[16*gi + 2*g2 + 1];
        v.z = tt32[16*gi + 8 + 2*g2];
        v.w = tt32[16*gi + 8 + 2*g2 + 1];
        ttab2[tid] = v;
    }

    // ================= frags (R10 verbatim except 2 stripes) ===============
    unsigned selA[3][4];
    #pragma unroll
    for (int p = 0; p < 3; ++p) {
        #pragma unroll
        for (int d = 0; d < 4; ++d) {
            const int k0 = grp*4 + (d & 1)*2 + (d >> 1)*16;
            const unsigned e0 = (((p + k0    ) % 3) == l16) ? 0x3F80u : 0u;
            const unsigned e1 = (((p + k0 + 1) % 3) == l16) ? 0x3F80u : 0u;
            selA[p][d] = e0 | (e1 << 16);
        }
    }
    const bf16x8 sel0 = mk8(selA[0][0], selA[0][1], selA[0][2], selA[0][3]);
    const bf16x8 sel1 = mk8(selA[1][0], selA[1][1], selA[1][2], selA[1][3]);
    const bf16x8 sel2 = mk8(selA[2][0], selA[2][1], selA[2][2], selA[2][3]);

    // 2 stripes per wave
    const int rowbase = blockIdx.x * 128 + wid * 32;
    float sf[2][3];
    bf16x8 bfv[2];
    #pragma unroll
    for (int i = 0; i < 2; ++i) {
        const int r = rowbase + i*16 + l16;
        float x0 = 1.f, x1 = 1.f, x2 = 1.f;
        if (r < B) { x0 = state[r*3+0]; x1 = state[r*3+1]; x2 = state[r*3+2]; }
        sf[i][0] = deadband(x0); sf[i][1] = deadband(x1); sf[i][2] = deadband(x2);
        const unsigned p0 = pkbf(sf[i][0], sf[i][1]);
        const unsigned p1 = bf16_rne(sf[i][2]);
        bfv[i] = mk8(low16 ? p0 : 0u, low16 ? p1 : 0u, 0u, 0u);
    }
    __syncthreads();   // ttab2 ready

    // ================= main: 24 groups x 2 stripes, no barriers ============
    const f32x4 cz = {0.f, 0.f, 0.f, 0.f};
    f32x4 cout0 = cz, cout1 = cz;

#define STRIPE(co, i)                                                          \
    {                                                                          \
        f32x4 c0 = __builtin_amdgcn_mfma_f32_16x16x32_bf16(af0, bfv[i], cz, 0, 0, 0); \
        f32x4 c1 = __builtin_amdgcn_mfma_f32_16x16x32_bf16(af1, bfv[i], cz, 0, 0, 0); \
        const unsigned d0 = csign(sgnpair(c0[1], c0[0]), tp.x);                \
        const unsigned d1 = csign(sgnpair(c0[3], c0[2]), tp.y);                \
        const unsigned d2 = csign(sgnpair(c1[1], c1[0]), tp.z);                \
        const unsigned d3 = csign(sgnpair(c1[3], c1[2]), tp.w);                \
        co = __builtin_amdgcn_mfma_f32_16x16x32_bf16(selv, mk8(d0, d1, d2, d3), co, 0, 0, 0); \
    }

    #pragma unroll
    for (int gi = 0; gi < 24; ++gi) {
        const uint2 dA = wtab[(2*gi)*16 + l16];      // LDS broadcast, 2-way max
        const uint2 dB = wtab[(2*gi+1)*16 + l16];
        const bf16x8 af0 = mk8(low16 ? dA.x : 0u, low16 ? dA.y : 0u, 0u, 0u);
        const bf16x8 af1 = mk8(low16 ? dB.x : 0u, low16 ? dB.y : 0u, 0u, 0u);
        const uint4 tp = ttab2[gi*4 + grp];          // one b128, broadcast
        const int p = (2*gi) % 3;                    // compile-time (unrolled)
        const bf16x8 selv = (p == 0) ? sel0 : (p == 1) ? sel1 : sel2;
        STRIPE(cout0, 0)
        STRIPE(cout1, 1)
    }
#undef STRIPE

    // ================= epilogue: base - acc, direct store ==================
    const float d00 = Ws0 + 0.001f, d11 = Ws3 + 0.001f, d22 = Ws5 + 0.001f;
#define EPI(co, i)                                                             \
    {                                                                          \
        const int r = rowbase + i*16 + l16;                                    \
        if (low16 && r < B) {                                                  \
            const float s0 = sf[i][0], s1 = sf[i][1], s2 = sf[i][2];           \
            out[r*3+0] = fmaf(s0, d00, fmaf(s1, Ws1, s2*Ws2)) - co[0];         \
            out[r*3+1] = fmaf(s0, Ws1, fmaf(s1, d11, s2*Ws4)) - co[1];         \
            out[r*3+2] = fmaf(s0, Ws2, fmaf(s1, Ws4, s2*d22)) - co[2];         \
        }                                                                      \
    }
    EPI(cout0, 0)
    EPI(cout1, 1)
#undef EPI
}

extern "C" void kernel_launch(void* const* d_in, const int* in_sizes, int n_in,
                              void* d_out, int out_size, void* d_ws, size_t ws_size,
                              hipStream_t stream) {
    const float* state = (const float*)d_in[0];
    const float* bvec  = (const float*)d_in[1];
    const float* lam   = (const float*)d_in[2];
    float* out = (float*)d_out;

    const int B = in_sizes[0] / 3;   // 131072

    const int grid = (B + 127) / 128;   // 128 rows per 256-thread block
    hipLaunchKernelGGL(policy_mfma3, dim3(grid), dim3(256), 0, stream,
                       state, bvec, lam, out, B);
}

// Round 13
// 17.981 us; speedup vs baseline: 1.3688x; 1.0462x over previous
//
#include <hip/hip_runtime.h>

// StablePolicy3phase (round 13): MFMA phase-A + VALU grouped accumulate.
//
// out[r,:] = s·(Wsum + 0.001 I) - sum_j copysign(t_j, v_j(r)) grouped by c=j%3
// Sign-trick validated R7-R12. Phase A (16x16x32 bf16 MFMA) computes
// v = s·W_row for 32 positions x 16 rows per group; the grouped sum is now
// pure VALU (bfi + add) instead of a selection-MFMA (R10-R12's phase C):
// a custom (head,comp)->position permutation makes the accumulator index
// c = (8*gi + 4*u + e) % 3 compile-time (lane-invariant), where the MFMA
// output C'[j=4g+e, row] has g = lane>>4. Final reduce over g = 2 shuffles.
// MFMA count 589,824 -> 393,216 (floor 4.65 -> 3.1 us); sel frags, ttab2,
// C-chain all deleted. Any permutation bug is bounded by 2*sum(t) = 0.3.
//
// Position map: h&3 = g;  m = 3*(h>>2)+c;  p = 32*(m>>3) + 16*((m>>2)&1) + 4*g + (m&3)
//   A-frag read (input layout m=l16):   wtab[gi*32 + u*16 + (lane&15)]
//   t read (output layout, g=lane>>4):  tf[gi*32 + u*16 + 4*g + e], b128 per u

typedef short bf16x8 __attribute__((ext_vector_type(8)));
typedef float f32x4  __attribute__((ext_vector_type(4)));

#define VMAX_T 1.03f   // VMAX - 0.02
#define VMIN_T 0.97f   // VMIN + 0.02
#define SCALE_C 0.15f

__device__ __forceinline__ float deadband(float x) {
    return fmaxf(x - VMAX_T, 0.f) - fmaxf(VMIN_T - x, 0.f);
}
__device__ __forceinline__ unsigned bf16_rne(float x) {
    unsigned u = __float_as_uint(x);
    return (u + 0x7FFFu + ((u >> 16) & 1u)) >> 16;   // RNE bf16 in low 16
}
__device__ __forceinline__ unsigned pkbf(float a, float b) {
    return bf16_rne(a) | (bf16_rne(b) << 16);
}
__device__ __forceinline__ bf16x8 mk8(unsigned a, unsigned b, unsigned c, unsigned d) {
    uint4 u; u.x = a; u.y = b; u.z = c; u.w = d;
    return __builtin_bit_cast(bf16x8, u);
}

__global__ __launch_bounds__(256) void policy_k13(
    const float* __restrict__ state,
    const float* __restrict__ bvec,
    const float* __restrict__ lam,
    float* __restrict__ out, int B)
{
    __shared__ uint2 wtab[768];   // 6 KB: bf16 A-frag dwords per position
    __shared__ float tf[768];     // 3 KB: exact f32 t per position
    __shared__ float red[4][8];

    const int tid  = threadIdx.x;
    const int lane = tid & 63;
    const int wid  = tid >> 6;
    const int l16  = lane & 15;
    const bool low16 = (lane < 16);

    // ================= head params (h = tid) ===============================
    const int h = tid;
    const float b0 = fmaxf(bvec[h*3+0], 0.f);
    const float b1 = fmaxf(bvec[h*3+1], 0.f);
    const float b2 = fmaxf(bvec[h*3+2], 0.f);
    float l0 = lam[h*6+0]; l0 *= l0;
    float l1 = lam[h*6+1]; l1 *= l1;
    float l2 = lam[h*6+2]; l2 *= l2;
    float l3 = lam[h*6+3]; l3 *= l3;
    float l4 = lam[h*6+4]; l4 *= l4;
    float l5 = lam[h*6+5]; l5 *= l5;
    // E order: (0,0),(1,0),(1,1),(2,0),(2,1),(2,2)
    const float w00 = l0+l1+l3, w01 = -l1, w02 = -l3;
    const float w11 = l1+l2+l4, w12 = -l4, w22 = l3+l4+l5;

    {   // block reduction of {bsum, Wsum x6}
        float v0 = b0+b1+b2, v1 = w00, v2 = w01, v3 = w02, v4 = w11, v5 = w12, v6 = w22;
        #pragma unroll
        for (int off = 32; off > 0; off >>= 1) {
            v0 += __shfl_down(v0, off, 64); v1 += __shfl_down(v1, off, 64);
            v2 += __shfl_down(v2, off, 64); v3 += __shfl_down(v3, off, 64);
            v4 += __shfl_down(v4, off, 64); v5 += __shfl_down(v5, off, 64);
            v6 += __shfl_down(v6, off, 64);
        }
        if (lane == 0) {
            red[wid][0]=v0; red[wid][1]=v1; red[wid][2]=v2; red[wid][3]=v3;
            red[wid][4]=v4; red[wid][5]=v5; red[wid][6]=v6;
        }
    }

    // W rows -> wtab at permuted positions (independent of the reduction)
    const float wr0[3] = {w00, w01, w02};
    const float wr1[3] = {w01, w11, w12};
    const float wr2[3] = {w02, w12, w22};
    int ppos[3];
    #pragma unroll
    for (int c = 0; c < 3; ++c) {
        const int m = 3*(h>>2) + c;
        const int p = ((m>>3)<<5) + (((m>>2)&1)<<4) + ((h&3)<<2) + (m&3);
        ppos[c] = p;
        uint2 wv;
        const float* wr = (c == 0) ? wr0 : (c == 1) ? wr1 : wr2;
        wv.x = pkbf(wr[0], wr[1]);
        wv.y = pkbf(wr[2], 0.f);
        wtab[p] = wv;
    }
    __syncthreads();

    const float S   = red[0][0]+red[1][0]+red[2][0]+red[3][0];
    const float Ws0 = red[0][1]+red[1][1]+red[2][1]+red[3][1];
    const float Ws1 = red[0][2]+red[1][2]+red[2][2]+red[3][2];
    const float Ws2 = red[0][3]+red[1][3]+red[2][3]+red[3][3];
    const float Ws3 = red[0][4]+red[1][4]+red[2][4]+red[3][4];
    const float Ws4 = red[0][5]+red[1][5]+red[2][5]+red[3][5];
    const float Ws5 = red[0][6]+red[1][6]+red[2][6]+red[3][6];
    const float inv = SCALE_C / S;

    tf[ppos[0]] = b0 * inv;
    tf[ppos[1]] = b1 * inv;
    tf[ppos[2]] = b2 * inv;

    // ================= state: 4 stripes per wave ===========================
    const int rowbase = blockIdx.x * 256 + wid * 64;
    float sf[4][3];
    bf16x8 bfv[4];
    #pragma unroll
    for (int i = 0; i < 4; ++i) {
        const int r = rowbase + i*16 + l16;
        float x0 = 1.f, x1 = 1.f, x2 = 1.f;
        if (r < B) { x0 = state[r*3+0]; x1 = state[r*3+1]; x2 = state[r*3+2]; }
        sf[i][0] = deadband(x0); sf[i][1] = deadband(x1); sf[i][2] = deadband(x2);
        const unsigned p0 = pkbf(sf[i][0], sf[i][1]);
        const unsigned p1 = bf16_rne(sf[i][2]);
        bfv[i] = mk8(low16 ? p0 : 0u, low16 ? p1 : 0u, 0u, 0u);
    }
    __syncthreads();   // wtab + tf ready

    // ================= main: 24 groups x 4 stripes =========================
    const f32x4 cz = {0.f, 0.f, 0.f, 0.f};
    float acc[3][4];
    #pragma unroll
    for (int c = 0; c < 3; ++c)
        #pragma unroll
        for (int i = 0; i < 4; ++i) acc[c][i] = 0.f;

    const int gsel = lane >> 4;   // output-layout g for the t reads

    #pragma unroll
    for (int gi = 0; gi < 24; ++gi) {
        // A-frags: input layout, lanes>=16 read aliased rows (x B=0 -> dead)
        const uint2 dA = wtab[gi*32 + l16];        // u = 0
        const uint2 dB = wtab[gi*32 + 16 + l16];   // u = 1
        const bf16x8 af0 = mk8(dA.x, dA.y, 0u, 0u);
        const bf16x8 af1 = mk8(dB.x, dB.y, 0u, 0u);
        // t: output layout, b128 per u (4 distinct addrs, 16-lane broadcast)
        const f32x4 t0v = *(const f32x4*)&tf[gi*32 + 4*gsel];
        const f32x4 t1v = *(const f32x4*)&tf[gi*32 + 16 + 4*gsel];

        #pragma unroll
        for (int i = 0; i < 4; ++i) {
            const f32x4 c0 = __builtin_amdgcn_mfma_f32_16x16x32_bf16(af0, bfv[i], cz, 0, 0, 0);
            const f32x4 c1 = __builtin_amdgcn_mfma_f32_16x16x32_bf16(af1, bfv[i], cz, 0, 0, 0);
            #pragma unroll
            for (int e = 0; e < 4; ++e) {
                acc[(8*gi + e) % 3][i]     += copysignf(t0v[e], c0[e]);
                acc[(8*gi + 4 + e) % 3][i] += copysignf(t1v[e], c1[e]);
            }
        }
    }

    // ================= reduce over g (lane bits 4,5) and store =============
    #pragma unroll
    for (int c = 0; c < 3; ++c)
        #pragma unroll
        for (int i = 0; i < 4; ++i) {
            acc[c][i] += __shfl_xor(acc[c][i], 16, 64);
            acc[c][i] += __shfl_xor(acc[c][i], 32, 64);
        }

    const float d00 = Ws0 + 0.001f, d11 = Ws3 + 0.001f, d22 = Ws5 + 0.001f;
    #pragma unroll
    for (int i = 0; i < 4; ++i) {
        const int r = rowbase + i*16 + l16;
        if (low16 && r < B) {
            const float s0 = sf[i][0], s1 = sf[i][1], s2 = sf[i][2];
            out[r*3+0] = fmaf(s0, d00, fmaf(s1, Ws1, s2*Ws2)) - acc[0][i];
            out[r*3+1] = fmaf(s0, Ws1, fmaf(s1, d11, s2*Ws4)) - acc[1][i];
            out[r*3+2] = fmaf(s0, Ws2, fmaf(s1, Ws4, s2*d22)) - acc[2][i];
        }
    }
}

extern "C" void kernel_launch(void* const* d_in, const int* in_sizes, int n_in,
                              void* d_out, int out_size, void* d_ws, size_t ws_size,
                              hipStream_t stream) {
    const float* state = (const float*)d_in[0];
    const float* bvec  = (const float*)d_in[1];
    const float* lam   = (const float*)d_in[2];
    float* out = (float*)d_out;

    const int B = in_sizes[0] / 3;   // 131072

    const int grid = (B + 255) / 256;   // 256 rows per 256-thread block
    hipLaunchKernelGGL(policy_k13, dim3(grid), dim3(256), 0, stream,
                       state, bvec, lam, out, B);
}